// Round 9
// baseline (48.848 us; speedup 1.0000x reference)
//
#include <hip/hip_runtime.h>

// spatial_adaptive_operator: B=4, H=W=128, N=16384, C=128, P=4
// d_in: [0]=x (B,N,C) f32, [1]=deltaA (B,N,C) f32, [2]=H, [3]=W, [4]=Wo (8,C) f32, [5]=bo (8,) f32
// d_out: out (B,N,C) f32  ++  sampling_locations (B,N,1,1,P,2) f32
//
// R8: pass A: 9-shfl compacting butterfly, NT input loads, same XCD swizzle
// as pass B (packed lines land in the consuming XCD's L2). pass B: 16 gathers
// batch-issued into an explicit array for MLP.

#define HW_ 128
#define CC_ 128
#define PP_ 4
#define NN_ (HW_ * HW_)

typedef float f32x4 __attribute__((ext_vector_type(4)));
typedef _Float16 f16x8 __attribute__((ext_vector_type(8)));

__device__ __forceinline__ int swizzled_work(int blk, int nblk) {
    // bijective XCD-chunked swizzle: XCD (blk&7) gets a contiguous work band
    const int q = nblk >> 3, r = nblk & 7;
    const int xcd = blk & 7;
    return (xcd < r ? xcd * (q + 1) : r * (q + 1) + (xcd - r) * q) + (blk >> 3);
}

// ---- Pass A: pack fp16 x||dA ; GEMV via compacting butterfly -> locs -------
__global__ __launch_bounds__(256) void sao_pack(
    const float* __restrict__ x,
    const float* __restrict__ dA,
    const float* __restrict__ Wo,
    const float* __restrict__ bo,
    float* __restrict__ locs,
    _Float16* __restrict__ packed)
{
    const int lane = threadIdx.x & 63;
    const int h = lane >> 5;          // which of the wave's 2 points
    const int s = lane & 31;          // sub-lane within the point
    const int wv = threadIdx.x >> 6;
    const int work = swizzled_work(blockIdx.x, gridDim.x);
    const int pt = work * 8 + wv * 2 + h;
    const size_t rowstart = (size_t)pt * CC_;

    // own 4 channels — read-once, non-temporal (don't evict packed from L2)
    const f32x4 xo = __builtin_nontemporal_load((const f32x4*)(x + rowstart + s * 4));
    const f32x4 dd = __builtin_nontemporal_load((const f32x4*)(dA + rowstart + s * 4));

    // Wo fragment: Wo[o][4s..4s+3], o=0..7 (4KB total -> L1-resident)
    float4 wf[8];
#pragma unroll
    for (int o = 0; o < 8; ++o)
        wf[o] = *(const float4*)(Wo + o * CC_ + s * 4);

    // pack: [x0..x3 d0..d3] fp16, 16B/lane -> 512B/pixel (cached store: pass B reads it)
    f16x8 pk;
    pk[0] = (_Float16)xo.x; pk[1] = (_Float16)xo.y;
    pk[2] = (_Float16)xo.z; pk[3] = (_Float16)xo.w;
    pk[4] = (_Float16)dd.x; pk[5] = (_Float16)dd.y;
    pk[6] = (_Float16)dd.z; pk[7] = (_Float16)dd.w;
    *(f16x8*)(packed + (size_t)pt * 256 + s * 8) = pk;

    // per-lane partials for all 8 outputs from own 4 channels (32 FMA)
    float p[8];
#pragma unroll
    for (int o = 0; o < 8; ++o)
        p[o] = xo.x * wf[o].x + xo.y * wf[o].y + xo.z * wf[o].z + xo.w * wf[o].w;

    // compacting butterfly: 8 values over 32 lanes in 9 shuffles.
    // level 1 (mask 1): 8 -> 4 values; lane keeps outputs with bit0 == (s&1)
    const int t0 = s & 1;
    float q4[4];
#pragma unroll
    for (int j = 0; j < 4; ++j) {
        const float keep = t0 ? p[2 * j + 1] : p[2 * j];
        const float send = t0 ? p[2 * j] : p[2 * j + 1];
        q4[j] = keep + __shfl_xor(send, 1);
    }
    // level 2 (mask 2): 4 -> 2; keep outputs with bit1 == (s>>1)&1
    const int t1 = (s >> 1) & 1;
    float r2[2];
#pragma unroll
    for (int i = 0; i < 2; ++i) {
        const float keep = t1 ? q4[2 * i + 1] : q4[2 * i];
        const float send = t1 ? q4[2 * i] : q4[2 * i + 1];
        r2[i] = keep + __shfl_xor(send, 2);
    }
    // level 3 (mask 4): 2 -> 1; keep output with bit2 == (s>>2)&1
    const int t2 = (s >> 2) & 1;
    {
        const float keep = t2 ? r2[1] : r2[0];
        const float send = t2 ? r2[0] : r2[1];
        r2[0] = keep + __shfl_xor(send, 4);
    }
    // levels 4,5: full sums; lane s now holds off-partial for output o = s&7
    r2[0] += __shfl_xor(r2[0], 8);
    r2[0] += __shfl_xor(r2[0], 16);

    if (s < 8) {   // o == s
        const float off = r2[0] + bo[s];
        const int n = pt & (NN_ - 1);
        const int ix = n & (HW_ - 1);
        const int iy = n >> 7;
        const float refx = (ix + 0.5f) * (1.0f / HW_);
        const float refy = (iy + 0.5f) * (1.0f / HW_);
        const float ref = (s & 1) ? refy : refx;
        locs[(size_t)pt * 8 + s] = ref + off * (1.0f / HW_);
    }
}

// ---- Pass B: fp16 bilinear gather + aggregate ------------------------------
__global__ __launch_bounds__(256) void sao_gather(
    const _Float16* __restrict__ packed,
    const float* __restrict__ locs,
    float* __restrict__ out)
{
    const int lane = threadIdx.x & 63;
    const int h = lane >> 5;
    const int s = lane & 31;
    const int wv = threadIdx.x >> 6;
    const int work = swizzled_work(blockIdx.x, gridDim.x);
    const int pt = work * 8 + wv * 2 + h;
    const int b = pt >> 14;
    const size_t rowstart = (size_t)pt * CC_;

    // sampling locations (uniform per half-wave)
    const f32x4 lo0 = *(const f32x4*)(locs + (size_t)pt * 8);
    const f32x4 lo1 = *(const f32x4*)(locs + (size_t)pt * 8 + 4);
    const float lx[4] = {lo0.x, lo0.z, lo1.x, lo1.z};
    const float ly[4] = {lo0.y, lo0.w, lo1.y, lo1.w};

    // own-row packed block: dA_own in elements 4..7
    const f16x8 own = *(const f16x8*)(packed + (size_t)pt * 256 + s * 8);

    // corner offsets + weights (bit-exact reference coord math)
    int eoff[PP_][4];
    float wgt[PP_][4];
#pragma unroll
    for (int p = 0; p < PP_; ++p) {
        const float gx = 2.0f * lx[p] - 1.0f;
        const float gy = 2.0f * ly[p] - 1.0f;
        const float xp = ((gx + 1.0f) * (float)HW_ - 1.0f) * 0.5f;
        const float yp = ((gy + 1.0f) * (float)HW_ - 1.0f) * 0.5f;
        const float x0f = floorf(xp), y0f = floorf(yp);
        const float wx1 = xp - x0f, wy1 = yp - y0f;
        const float wx0 = 1.0f - wx1, wy0 = 1.0f - wy1;
        const int ix0 = (int)x0f, iy0 = (int)y0f;
#pragma unroll
        for (int k = 0; k < 4; ++k) {
            const int cx = ix0 + (k & 1);
            const int cy = iy0 + (k >> 1);
            const bool valid = (cx >= 0) & (cx < HW_) & (cy >= 0) & (cy < HW_);
            float w = ((k & 1) ? wx1 : wx0) * ((k >> 1) ? wy1 : wy0);
            wgt[p][k] = valid ? w : 0.0f;
            const int pix = min(max(cy, 0), HW_ - 1) * HW_ + min(max(cx, 0), HW_ - 1);
            eoff[p][k] = pix * 256;            // fp16 element offset within batch
        }
    }

    const _Float16* pb = packed + (size_t)b * ((size_t)NN_ * 256) + s * 8;

    // batch-issue ALL 16 gathers first (MLP), then accumulate
    f16x8 g[16];
#pragma unroll
    for (int p = 0; p < PP_; ++p)
#pragma unroll
        for (int k = 0; k < 4; ++k)
            g[p * 4 + k] = *(const f16x8*)(pb + eoff[p][k]);

    f16x8 fw[PP_];
#pragma unroll
    for (int p = 0; p < PP_; ++p) {
        fw[p] = g[p * 4 + 0] * (_Float16)wgt[p][0]
              + g[p * 4 + 1] * (_Float16)wgt[p][1]
              + g[p * 4 + 2] * (_Float16)wgt[p][2]
              + g[p * 4 + 3] * (_Float16)wgt[p][3];
    }

    // combine in f32: acc_c += feat_c * (wt_c - dA_own_c)
    f32x4 acc;
    acc.x = acc.y = acc.z = acc.w = 0.0f;
    const float d0 = (float)own[4], d1 = (float)own[5];
    const float d2 = (float)own[6], d3 = (float)own[7];
#pragma unroll
    for (int p = 0; p < PP_; ++p) {
        acc.x = fmaf((float)fw[p][0], (float)fw[p][4] - d0, acc.x);
        acc.y = fmaf((float)fw[p][1], (float)fw[p][5] - d1, acc.y);
        acc.z = fmaf((float)fw[p][2], (float)fw[p][6] - d2, acc.z);
        acc.w = fmaf((float)fw[p][3], (float)fw[p][7] - d3, acc.w);
    }

    f32x4 res;
    res.x = acc.x * 0.25f;
    res.y = acc.y * 0.25f;
    res.z = acc.z * 0.25f;
    res.w = acc.w * 0.25f;
    __builtin_nontemporal_store(res, (f32x4*)(out + rowstart + s * 4));
}

// ---- Fallback: fused f32 kernel (known-good) if ws too small ---------------
__global__ __launch_bounds__(256) void sao_fused(
    const float* __restrict__ x,
    const float* __restrict__ dA,
    const float* __restrict__ Wo,
    const float* __restrict__ bo,
    float* __restrict__ out,
    float* __restrict__ locs)
{
    const int lane = threadIdx.x & 63;
    const int h = lane >> 5;
    const int s = lane & 31;
    const int wv = threadIdx.x >> 6;
    const int work = swizzled_work(blockIdx.x, gridDim.x);
    const int pt = work * 8 + wv * 2 + h;
    const int b = pt >> 14;
    const int n = pt & (NN_ - 1);
    const int ix = n & (HW_ - 1);
    const int iy = n >> 7;
    const size_t rowstart = (size_t)pt * CC_;
    const float4 d4 = *(const float4*)(dA + rowstart + s * 4);
    const int o = s & 7;
    const int chunk = s >> 3;
    const float* xr = x + rowstart + chunk * 32;
    const float* wr = Wo + o * CC_ + chunk * 32;
    float partial = 0.0f;
#pragma unroll
    for (int j = 0; j < 8; ++j) {
        const float4 xv = *(const float4*)(xr + 4 * j);
        const float4 wvv = *(const float4*)(wr + 4 * j);
        partial += xv.x * wvv.x + xv.y * wvv.y + xv.z * wvv.z + xv.w * wvv.w;
    }
    partial += __shfl_xor(partial, 8);
    partial += __shfl_xor(partial, 16);
    const float offv = partial + bo[o];
    const float refx = (ix + 0.5f) * (1.0f / HW_);
    const float refy = (iy + 0.5f) * (1.0f / HW_);
    if (s < 8) {
        const float ref = (o & 1) ? refy : refx;
        locs[(size_t)pt * 8 + o] = ref + offv * (1.0f / HW_);
    }
    float offs[8];
#pragma unroll
    for (int oo = 0; oo < 8; ++oo)
        offs[oo] = __shfl(offv, oo, 32);
    const size_t bbase = (size_t)b * (size_t)(NN_ * CC_) + s * 4;
    float4 acc = make_float4(0.f, 0.f, 0.f, 0.f);
#pragma unroll
    for (int p = 0; p < PP_; ++p) {
        const float locx = refx + offs[2 * p] * (1.0f / HW_);
        const float locy = refy + offs[2 * p + 1] * (1.0f / HW_);
        const float gx = 2.0f * locx - 1.0f;
        const float gy = 2.0f * locy - 1.0f;
        const float xp = ((gx + 1.0f) * (float)HW_ - 1.0f) * 0.5f;
        const float yp = ((gy + 1.0f) * (float)HW_ - 1.0f) * 0.5f;
        const float x0f = floorf(xp), y0f = floorf(yp);
        const float wx1 = xp - x0f, wy1 = yp - y0f;
        const float wx0 = 1.0f - wx1, wy0 = 1.0f - wy1;
        const int ix0 = (int)x0f, iy0 = (int)y0f;
        float4 feat = make_float4(0.f, 0.f, 0.f, 0.f);
        float4 wt = make_float4(0.f, 0.f, 0.f, 0.f);
#pragma unroll
        for (int k = 0; k < 4; ++k) {
            const int cx = ix0 + (k & 1);
            const int cy = iy0 + (k >> 1);
            const bool valid = (cx >= 0) & (cx < HW_) & (cy >= 0) & (cy < HW_);
            float w = ((k & 1) ? wx1 : wx0) * ((k >> 1) ? wy1 : wy0);
            w = valid ? w : 0.0f;
            const int pix = min(max(cy, 0), HW_ - 1) * HW_ + min(max(cx, 0), HW_ - 1);
            const size_t cb = bbase + (size_t)pix * CC_;
            const float4 xv = *(const float4*)(x + cb);
            const float4 dv = *(const float4*)(dA + cb);
            feat.x = fmaf(w, xv.x, feat.x);
            feat.y = fmaf(w, xv.y, feat.y);
            feat.z = fmaf(w, xv.z, feat.z);
            feat.w = fmaf(w, xv.w, feat.w);
            wt.x = fmaf(w, dv.x, wt.x);
            wt.y = fmaf(w, dv.y, wt.y);
            wt.z = fmaf(w, dv.z, wt.z);
            wt.w = fmaf(w, dv.w, wt.w);
        }
        acc.x = fmaf(feat.x, wt.x - d4.x, acc.x);
        acc.y = fmaf(feat.y, wt.y - d4.y, acc.y);
        acc.z = fmaf(feat.z, wt.z - d4.z, acc.z);
        acc.w = fmaf(feat.w, wt.w - d4.w, acc.w);
    }
    f32x4 res;
    res.x = acc.x * 0.25f;
    res.y = acc.y * 0.25f;
    res.z = acc.z * 0.25f;
    res.w = acc.w * 0.25f;
    __builtin_nontemporal_store(res, (f32x4*)(out + rowstart + s * 4));
}

extern "C" void kernel_launch(void* const* d_in, const int* in_sizes, int n_in,
                              void* d_out, int out_size, void* d_ws, size_t ws_size,
                              hipStream_t stream) {
    const float* x = (const float*)d_in[0];
    const float* dA = (const float*)d_in[1];
    const float* Wo = (const float*)d_in[4];
    const float* bo = (const float*)d_in[5];
    float* out = (float*)d_out;

    const int points = in_sizes[0] / CC_;               // B*N = 65536
    float* locs = out + (size_t)points * CC_;           // second tuple output
    const int blocks = points / 8;

    const size_t need = (size_t)points * 256 * sizeof(_Float16);  // 32 MB
    if (ws_size >= need) {
        _Float16* packed = (_Float16*)d_ws;
        sao_pack<<<blocks, 256, 0, stream>>>(x, dA, Wo, bo, locs, packed);
        sao_gather<<<blocks, 256, 0, stream>>>(packed, locs, out);
    } else {
        sao_fused<<<blocks, 256, 0, stream>>>(x, dA, Wo, bo, out, locs);
    }
}

// Round 10
// 46.794 us; speedup vs baseline: 1.0439x; 1.0439x over previous
//
#include <hip/hip_runtime.h>

// spatial_adaptive_operator: B=4, H=W=128, N=16384, C=128, P=4
// d_in: [0]=x (B,N,C) f32, [1]=deltaA (B,N,C) f32, [2]=H, [3]=W, [4]=Wo (8,C) f32, [5]=bo (8,) f32
// d_out: out (B,N,C) f32  ++  sampling_locations (B,N,1,1,P,2) f32
//
// R9 = exact revert to R7 (best verified: 45.9us).
//  Pass A: pack fp16 x||dA into d_ws; GEMV reuses the pack-load float4
//          (no extra x reads) + 5-level x8 butterfly. ~22us (HBM-stream).
//  Pass B: fp16 bilinear gather from packed (512B/corner) + aggregate. ~24us
//          (L2-BW-bound at ~20 TB/s effective gather rate).
// R8's bundled tweaks (compacting butterfly, NT loads, pass-A swizzle,
// batched g[16]) regressed to 48.8us -> reverted.

#define HW_ 128
#define CC_ 128
#define PP_ 4
#define NN_ (HW_ * HW_)

typedef float f32x4 __attribute__((ext_vector_type(4)));
typedef _Float16 f16x8 __attribute__((ext_vector_type(8)));

// ---- Pass A: pack fp16 x||dA ; GEMV via butterfly -> locs ------------------
__global__ __launch_bounds__(256) void sao_pack(
    const float* __restrict__ x,
    const float* __restrict__ dA,
    const float* __restrict__ Wo,
    const float* __restrict__ bo,
    float* __restrict__ locs,
    _Float16* __restrict__ packed)
{
    const int lane = threadIdx.x & 63;
    const int h = lane >> 5;          // which of the wave's 2 points
    const int s = lane & 31;          // sub-lane within the point
    const int wv = threadIdx.x >> 6;
    const int pt = blockIdx.x * 8 + wv * 2 + h;
    const size_t rowstart = (size_t)pt * CC_;

    // own 4 channels (single read of x serves BOTH pack and GEMV)
    const float4 xo = *(const float4*)(x + rowstart + s * 4);
    const float4 dd = *(const float4*)(dA + rowstart + s * 4);

    // Wo fragment: Wo[o][4s..4s+3], o=0..7  (4KB total -> L1-resident)
    float4 wf[8];
#pragma unroll
    for (int o = 0; o < 8; ++o)
        wf[o] = *(const float4*)(Wo + o * CC_ + s * 4);

    // pack: [x0..x3 d0..d3] fp16, 16B/lane -> 512B/pixel
    f16x8 pk;
    pk[0] = (_Float16)xo.x; pk[1] = (_Float16)xo.y;
    pk[2] = (_Float16)xo.z; pk[3] = (_Float16)xo.w;
    pk[4] = (_Float16)dd.x; pk[5] = (_Float16)dd.y;
    pk[6] = (_Float16)dd.z; pk[7] = (_Float16)dd.w;
    *(f16x8*)(packed + (size_t)pt * 256 + s * 8) = pk;

    // per-lane partials for all 8 outputs from own 4 channels
    float p[8];
#pragma unroll
    for (int o = 0; o < 8; ++o)
        p[o] = xo.x * wf[o].x + xo.y * wf[o].y + xo.z * wf[o].z + xo.w * wf[o].w;

    // butterfly sum across the 32-lane half (masks <32 never cross halves)
#pragma unroll
    for (int m = 1; m <= 16; m <<= 1) {
#pragma unroll
        for (int o = 0; o < 8; ++o)
            p[o] += __shfl_xor(p[o], m);
    }

    // lanes s<8 store locs element s (static-index select from p[])
    if (s < 8) {
        float off = 0.0f;
#pragma unroll
        for (int o = 0; o < 8; ++o)
            if (o == s) off = p[o];
        off += bo[s];
        const int n = pt & (NN_ - 1);
        const int ix = n & (HW_ - 1);
        const int iy = n >> 7;
        const float refx = (ix + 0.5f) * (1.0f / HW_);
        const float refy = (iy + 0.5f) * (1.0f / HW_);
        const float ref = (s & 1) ? refy : refx;
        locs[(size_t)pt * 8 + s] = ref + off * (1.0f / HW_);
    }
}

// ---- Pass B: fp16 bilinear gather + aggregate ------------------------------
__global__ __launch_bounds__(256) void sao_gather(
    const _Float16* __restrict__ packed,
    const float* __restrict__ locs,
    float* __restrict__ out)
{
    const int lane = threadIdx.x & 63;
    const int h = lane >> 5;
    const int s = lane & 31;
    const int wv = threadIdx.x >> 6;

    // bijective XCD-chunked swizzle
    const int nblk = gridDim.x;
    const int q = nblk >> 3, r = nblk & 7;
    const int xcd = blockIdx.x & 7;
    const int work = (xcd < r ? xcd * (q + 1) : r * (q + 1) + (xcd - r) * q)
                     + (blockIdx.x >> 3);

    const int pt = work * 8 + wv * 2 + h;
    const int b = pt >> 14;
    const size_t rowstart = (size_t)pt * CC_;

    // sampling locations (uniform per half-wave)
    const f32x4 lo0 = *(const f32x4*)(locs + (size_t)pt * 8);
    const f32x4 lo1 = *(const f32x4*)(locs + (size_t)pt * 8 + 4);
    const float lx[4] = {lo0.x, lo0.z, lo1.x, lo1.z};
    const float ly[4] = {lo0.y, lo0.w, lo1.y, lo1.w};

    // own-row packed block: dA_own in elements 4..7
    const f16x8 own = *(const f16x8*)(packed + (size_t)pt * 256 + s * 8);

    // corner offsets + weights (bit-exact reference coord math)
    int eoff[PP_][4];
    float wgt[PP_][4];
#pragma unroll
    for (int p = 0; p < PP_; ++p) {
        const float gx = 2.0f * lx[p] - 1.0f;
        const float gy = 2.0f * ly[p] - 1.0f;
        const float xp = ((gx + 1.0f) * (float)HW_ - 1.0f) * 0.5f;
        const float yp = ((gy + 1.0f) * (float)HW_ - 1.0f) * 0.5f;
        const float x0f = floorf(xp), y0f = floorf(yp);
        const float wx1 = xp - x0f, wy1 = yp - y0f;
        const float wx0 = 1.0f - wx1, wy0 = 1.0f - wy1;
        const int ix0 = (int)x0f, iy0 = (int)y0f;
#pragma unroll
        for (int k = 0; k < 4; ++k) {
            const int cx = ix0 + (k & 1);
            const int cy = iy0 + (k >> 1);
            const bool valid = (cx >= 0) & (cx < HW_) & (cy >= 0) & (cy < HW_);
            float w = ((k & 1) ? wx1 : wx0) * ((k >> 1) ? wy1 : wy0);
            wgt[p][k] = valid ? w : 0.0f;
            const int pix = min(max(cy, 0), HW_ - 1) * HW_ + min(max(cx, 0), HW_ - 1);
            eoff[p][k] = pix * 256;            // fp16 element offset within batch
        }
    }

    const _Float16* pb = packed + (size_t)b * ((size_t)NN_ * 256) + s * 8;

    // gather + packed-fp16 accumulate: fw[p] = [feat ch0..3 | wt ch0..3]
    f16x8 fw[PP_];
#pragma unroll
    for (int p = 0; p < PP_; ++p) {
        f16x8 a0 = *(const f16x8*)(pb + eoff[p][0]);
        f16x8 a1 = *(const f16x8*)(pb + eoff[p][1]);
        f16x8 a2 = *(const f16x8*)(pb + eoff[p][2]);
        f16x8 a3 = *(const f16x8*)(pb + eoff[p][3]);
        fw[p] = a0 * (_Float16)wgt[p][0] + a1 * (_Float16)wgt[p][1]
              + a2 * (_Float16)wgt[p][2] + a3 * (_Float16)wgt[p][3];
    }

    // combine in f32: acc_c += feat_c * (wt_c - dA_own_c)
    f32x4 acc;
    acc.x = acc.y = acc.z = acc.w = 0.0f;
    const float d0 = (float)own[4], d1 = (float)own[5];
    const float d2 = (float)own[6], d3 = (float)own[7];
#pragma unroll
    for (int p = 0; p < PP_; ++p) {
        acc.x = fmaf((float)fw[p][0], (float)fw[p][4] - d0, acc.x);
        acc.y = fmaf((float)fw[p][1], (float)fw[p][5] - d1, acc.y);
        acc.z = fmaf((float)fw[p][2], (float)fw[p][6] - d2, acc.z);
        acc.w = fmaf((float)fw[p][3], (float)fw[p][7] - d3, acc.w);
    }

    f32x4 res;
    res.x = acc.x * 0.25f;
    res.y = acc.y * 0.25f;
    res.z = acc.z * 0.25f;
    res.w = acc.w * 0.25f;
    __builtin_nontemporal_store(res, (f32x4*)(out + rowstart + s * 4));
}

// ---- Fallback: fused f32 kernel (known-good) if ws too small ---------------
__global__ __launch_bounds__(256) void sao_fused(
    const float* __restrict__ x,
    const float* __restrict__ dA,
    const float* __restrict__ Wo,
    const float* __restrict__ bo,
    float* __restrict__ out,
    float* __restrict__ locs)
{
    const int lane = threadIdx.x & 63;
    const int h = lane >> 5;
    const int s = lane & 31;
    const int wv = threadIdx.x >> 6;
    const int nblk = gridDim.x;
    const int q = nblk >> 3, r = nblk & 7;
    const int xcd = blockIdx.x & 7;
    const int work = (xcd < r ? xcd * (q + 1) : r * (q + 1) + (xcd - r) * q)
                     + (blockIdx.x >> 3);
    const int pt = work * 8 + wv * 2 + h;
    const int b = pt >> 14;
    const int n = pt & (NN_ - 1);
    const int ix = n & (HW_ - 1);
    const int iy = n >> 7;
    const size_t rowstart = (size_t)pt * CC_;
    const float4 d4 = *(const float4*)(dA + rowstart + s * 4);
    const int o = s & 7;
    const int chunk = s >> 3;
    const float* xr = x + rowstart + chunk * 32;
    const float* wr = Wo + o * CC_ + chunk * 32;
    float partial = 0.0f;
#pragma unroll
    for (int j = 0; j < 8; ++j) {
        const float4 xv = *(const float4*)(xr + 4 * j);
        const float4 wvv = *(const float4*)(wr + 4 * j);
        partial += xv.x * wvv.x + xv.y * wvv.y + xv.z * wvv.z + xv.w * wvv.w;
    }
    partial += __shfl_xor(partial, 8);
    partial += __shfl_xor(partial, 16);
    const float offv = partial + bo[o];
    const float refx = (ix + 0.5f) * (1.0f / HW_);
    const float refy = (iy + 0.5f) * (1.0f / HW_);
    if (s < 8) {
        const float ref = (o & 1) ? refy : refx;
        locs[(size_t)pt * 8 + o] = ref + offv * (1.0f / HW_);
    }
    float offs[8];
#pragma unroll
    for (int oo = 0; oo < 8; ++oo)
        offs[oo] = __shfl(offv, oo, 32);
    const size_t bbase = (size_t)b * (size_t)(NN_ * CC_) + s * 4;
    float4 acc = make_float4(0.f, 0.f, 0.f, 0.f);
#pragma unroll
    for (int p = 0; p < PP_; ++p) {
        const float locx = refx + offs[2 * p] * (1.0f / HW_);
        const float locy = refy + offs[2 * p + 1] * (1.0f / HW_);
        const float gx = 2.0f * locx - 1.0f;
        const float gy = 2.0f * locy - 1.0f;
        const float xp = ((gx + 1.0f) * (float)HW_ - 1.0f) * 0.5f;
        const float yp = ((gy + 1.0f) * (float)HW_ - 1.0f) * 0.5f;
        const float x0f = floorf(xp), y0f = floorf(yp);
        const float wx1 = xp - x0f, wy1 = yp - y0f;
        const float wx0 = 1.0f - wx1, wy0 = 1.0f - wy1;
        const int ix0 = (int)x0f, iy0 = (int)y0f;
        float4 feat = make_float4(0.f, 0.f, 0.f, 0.f);
        float4 wt = make_float4(0.f, 0.f, 0.f, 0.f);
#pragma unroll
        for (int k = 0; k < 4; ++k) {
            const int cx = ix0 + (k & 1);
            const int cy = iy0 + (k >> 1);
            const bool valid = (cx >= 0) & (cx < HW_) & (cy >= 0) & (cy < HW_);
            float w = ((k & 1) ? wx1 : wx0) * ((k >> 1) ? wy1 : wy0);
            w = valid ? w : 0.0f;
            const int pix = min(max(cy, 0), HW_ - 1) * HW_ + min(max(cx, 0), HW_ - 1);
            const size_t cb = bbase + (size_t)pix * CC_;
            const float4 xv = *(const float4*)(x + cb);
            const float4 dv = *(const float4*)(dA + cb);
            feat.x = fmaf(w, xv.x, feat.x);
            feat.y = fmaf(w, xv.y, feat.y);
            feat.z = fmaf(w, xv.z, feat.z);
            feat.w = fmaf(w, xv.w, feat.w);
            wt.x = fmaf(w, dv.x, wt.x);
            wt.y = fmaf(w, dv.y, wt.y);
            wt.z = fmaf(w, dv.z, wt.z);
            wt.w = fmaf(w, dv.w, wt.w);
        }
        acc.x = fmaf(feat.x, wt.x - d4.x, acc.x);
        acc.y = fmaf(feat.y, wt.y - d4.y, acc.y);
        acc.z = fmaf(feat.z, wt.z - d4.z, acc.z);
        acc.w = fmaf(feat.w, wt.w - d4.w, acc.w);
    }
    f32x4 res;
    res.x = acc.x * 0.25f;
    res.y = acc.y * 0.25f;
    res.z = acc.z * 0.25f;
    res.w = acc.w * 0.25f;
    __builtin_nontemporal_store(res, (f32x4*)(out + rowstart + s * 4));
}

extern "C" void kernel_launch(void* const* d_in, const int* in_sizes, int n_in,
                              void* d_out, int out_size, void* d_ws, size_t ws_size,
                              hipStream_t stream) {
    const float* x = (const float*)d_in[0];
    const float* dA = (const float*)d_in[1];
    const float* Wo = (const float*)d_in[4];
    const float* bo = (const float*)d_in[5];
    float* out = (float*)d_out;

    const int points = in_sizes[0] / CC_;               // B*N = 65536
    float* locs = out + (size_t)points * CC_;           // second tuple output
    const int blocks = points / 8;

    const size_t need = (size_t)points * 256 * sizeof(_Float16);  // 32 MB
    if (ws_size >= need) {
        _Float16* packed = (_Float16*)d_ws;
        sao_pack<<<blocks, 256, 0, stream>>>(x, dA, Wo, bo, locs, packed);
        sao_gather<<<blocks, 256, 0, stream>>>(packed, locs, out);
    } else {
        sao_fused<<<blocks, 256, 0, stream>>>(x, dA, Wo, bo, out, locs);
    }
}